// Round 6
// baseline (323.735 us; speedup 1.0000x reference)
//
#include <hip/hip_runtime.h>
#include <hip/hip_bf16.h>
#include <stdint.h>

#define N_Q   16384
#define N_CLS 1024
#define DIM_H 2048

typedef __bf16 bf16x8 __attribute__((ext_vector_type(8)));
typedef float  f32x4  __attribute__((ext_vector_type(4)));

__device__ __forceinline__ uint32_t f2bf(float f) {
    uint32_t u = __float_as_uint(f);
    u += 0x7fff + ((u >> 16) & 1);   // RNE
    return u >> 16;
}
// pack two fp32 -> two bf16 (round-to-nearest ties-away): 2 adds + 1 merge
__device__ __forceinline__ uint32_t pk2(float a, float b) {
    uint32_t ua = __float_as_uint(a) + 0x8000u;
    uint32_t ub = __float_as_uint(b) + 0x8000u;
    return (ua >> 16) | (ub & 0xFFFF0000u);
}

// direct-to-LDS 16B staging; HW dest = wave-uniform base + lane*16
__device__ __forceinline__ void load_lds16(const __bf16* g, __bf16* l) {
    __builtin_amdgcn_global_load_lds(
        (const __attribute__((address_space(1))) uint32_t*)g,
        (__attribute__((address_space(3))) uint32_t*)l, 16, 0, 0);
}

// prepass: cls_bf16[c*H+h] = bf16(cls_f32[c*H+h] * M_f32[h])  (4 MB out)
__global__ void scale_cls_kernel(const float* __restrict__ cls,
                                 const float* __restrict__ M,
                                 uint16_t* __restrict__ o) {
    size_t e = ((size_t)blockIdx.x * 256 + threadIdx.x) * 4;
    float4 c = *(const float4*)(cls + e);
    float4 m = *(const float4*)(M + (e & (DIM_H - 1)));
    uint32_t lo = f2bf(c.x * m.x) | (f2bf(c.y * m.y) << 16);
    uint32_t hi = f2bf(c.z * m.z) | (f2bf(c.w * m.w) << 16);
    *(uint2*)(o + e) = make_uint2(lo, hi);
}

// 128x128 tile, BK=64, 4 waves, 4x4 mfma_f32_16x16x32_bf16 per wave.
// A (q, fp32) fused: VGPR-prefetched one tile ahead -> pack -> ds_write_b128.
//   k+1 loads issued pre-barrier so their latency drains alongside B's DMA.
// B (cls, bf16 pre-scaled) staged via async global_load_lds.
// LDS XOR-8 swizzle (R4/R5-verified): chunk (row r, pos p) holds k-chunk p^(r&7).
// Block mapping (R5-verified, FETCH~=ideal): xcd=b&7 owns 16 row-panels, col fastest.
__global__ __launch_bounds__(256)
void gemm_fused_kernel(const float* __restrict__ Q,      // (N,H) fp32
                       const uint16_t* __restrict__ Bp,  // (C,H) bf16
                       float* __restrict__ Out) {        // (N,C) fp32
    __shared__ __align__(16) __bf16 As[128 * 64];
    __shared__ __align__(16) __bf16 Bs[128 * 64];

    const int tid  = threadIdx.x;
    const int lane = tid & 63;
    const int wave = tid >> 6;

    const int b    = blockIdx.x;                    // 0..1023
    const int xcd  = b & 7;
    const int t    = b >> 3;                        // 0..127
    const int row0 = (xcd * 16 + (t >> 3)) * 128;   // query rows
    const int col0 = (t & 7) * 128;                 // class cols

    const int wm   = (wave >> 1) * 64;
    const int wn   = (wave & 1) * 64;
    const int frow = lane & 15;
    const int fq   = lane >> 4;

    const __bf16* B = (const __bf16*)Bp;

    // per-thread A-unit geometry (4 units of 8 elems = 32 fp32/thread)
    int ur[4], ukc[4];
    const float* asrc[4];
#pragma unroll
    for (int i = 0; i < 4; ++i) {
        const int u = tid + 256 * i;
        ur[i]  = u >> 3;                            // tile row 0..127
        ukc[i] = u & 7;                             // 16B k-chunk 0..7
        asrc[i] = Q + (size_t)(row0 + ur[i]) * DIM_H + ukc[i] * 8;
    }

    f32x4 acc[4][4] = {};
    float4 areg[8];

    // prologue: prefetch A tile k0=0
#pragma unroll
    for (int i = 0; i < 4; ++i) {
        areg[2 * i]     = *(const float4*)(asrc[i]);
        areg[2 * i + 1] = *(const float4*)(asrc[i] + 4);
    }

    for (int k0 = 0; k0 < DIM_H; k0 += 64) {
        // ---- B tile: async global->LDS, swizzled chunk choice ----
#pragma unroll
        for (int i = 0; i < 4; ++i) {
            const int chunkbase = (i * 4 + wave) * 64;   // wave-uniform
            const int c = chunkbase + lane;
            const int r = c >> 3;
            const int g = (c & 7) ^ (r & 7);
            load_lds16(B + (size_t)(col0 + r) * DIM_H + k0 + g * 8,
                       &Bs[chunkbase * 8]);
        }
        // ---- A tile: pack prefetched regs -> swizzled ds_write_b128 ----
#pragma unroll
        for (int i = 0; i < 4; ++i) {
            float4 a = areg[2 * i], bb = areg[2 * i + 1];
            uint4 w = make_uint4(pk2(a.x, a.y), pk2(a.z, a.w),
                                 pk2(bb.x, bb.y), pk2(bb.z, bb.w));
            const int p = ukc[i] ^ (ur[i] & 7);
            *(uint4*)&As[ur[i] * 64 + p * 8] = w;
        }
        // ---- issue A loads for next tile (drain with B DMA at barrier) ----
        if (k0 + 64 < DIM_H) {
#pragma unroll
            for (int i = 0; i < 4; ++i) {
                areg[2 * i]     = *(const float4*)(asrc[i] + k0 + 64);
                areg[2 * i + 1] = *(const float4*)(asrc[i] + k0 + 68);
            }
        }
        __syncthreads();

        // ---- compute: 2 k-steps x 16 MFMA, swizzled fragment reads ----
#pragma unroll
        for (int ks = 0; ks < 2; ++ks) {
            bf16x8 af[4], bfr[4];
#pragma unroll
            for (int tt = 0; tt < 4; ++tt) {
                const int ra = wm + tt * 16 + frow;
                const int pa = ((ks * 4 + fq) ^ (ra & 7)) * 8;
                af[tt] = *(const bf16x8*)&As[ra * 64 + pa];
                const int rb = wn + tt * 16 + frow;
                const int pb = ((ks * 4 + fq) ^ (rb & 7)) * 8;
                bfr[tt] = *(const bf16x8*)&Bs[rb * 64 + pb];
            }
#pragma unroll
            for (int i = 0; i < 4; ++i)
#pragma unroll
                for (int j = 0; j < 4; ++j)
                    acc[i][j] = __builtin_amdgcn_mfma_f32_16x16x32_bf16(
                        af[i], bfr[j], acc[i][j], 0, 0, 0);
        }
        __syncthreads();
    }

    // ---- epilogue: C/D layout col=lane&15, row=(lane>>4)*4+reg; fp32 out ----
#pragma unroll
    for (int i = 0; i < 4; ++i) {
#pragma unroll
        for (int j = 0; j < 4; ++j) {
            const int row = row0 + wm + i * 16 + fq * 4;
            const int col = col0 + wn + j * 16 + frow;
#pragma unroll
            for (int r = 0; r < 4; ++r)
                Out[(size_t)(row + r) * N_CLS + col] = acc[i][j][r];
        }
    }
}

// correctness fallback (fp32 end-to-end) if workspace is too small
__global__ void naive_kernel(const float* __restrict__ Q,
                             const float* __restrict__ C,
                             const float* __restrict__ M,
                             float* __restrict__ Out) {
    size_t idx = (size_t)blockIdx.x * 256 + threadIdx.x;
    int n = (int)(idx >> 10), c = (int)(idx & (N_CLS - 1));
    float s = 0.f;
    for (int h = 0; h < DIM_H; ++h)
        s += Q[(size_t)n * DIM_H + h] * C[(size_t)c * DIM_H + h] * M[h];
    Out[idx] = s;
}

extern "C" void kernel_launch(void* const* d_in, const int* in_sizes, int n_in,
                              void* d_out, int out_size, void* d_ws, size_t ws_size,
                              hipStream_t stream) {
    const float* cls = (const float*)d_in[0];   // (C,H)  = 2,097,152
    const float* q   = (const float*)d_in[1];   // (N,H)  = 33,554,432
    const float* M   = (const float*)d_in[2];   // (H,1)  = 2,048
    for (int i = 0; i < n_in; ++i) {
        if      (in_sizes[i] == N_CLS * DIM_H) cls = (const float*)d_in[i];
        else if (in_sizes[i] == N_Q * DIM_H)   q   = (const float*)d_in[i];
        else if (in_sizes[i] == DIM_H)         M   = (const float*)d_in[i];
    }
    float* out = (float*)d_out;

    const size_t cls_bytes = (size_t)N_CLS * DIM_H * sizeof(uint16_t);  // 4 MB
    if (ws_size >= cls_bytes) {
        uint16_t* cls_bf = (uint16_t*)d_ws;
        scale_cls_kernel<<<(N_CLS * DIM_H) / (256 * 4), 256, 0, stream>>>(cls, M, cls_bf);
        gemm_fused_kernel<<<(N_Q / 128) * (N_CLS / 128), 256, 0, stream>>>(q, cls_bf, out);
    } else {
        naive_kernel<<<(unsigned)(((size_t)N_Q * N_CLS) / 256), 256, 0, stream>>>(q, cls, M, out);
    }
}